// Round 13
// baseline (158.032 us; speedup 1.0000x reference)
//
#include <hip/hip_runtime.h>
#include <hip/hip_bf16.h>

#define L_    4096
#define DIN   512
#define DOUT  256
#define NH    4
#define HD    64
#define JW    128                      // L_/32 j-words per row

typedef unsigned short u16;
typedef __attribute__((ext_vector_type(8))) short short8;   // 8 x bf16
typedef __attribute__((ext_vector_type(4))) float floatx4;  // MFMA C/D frag

#define VMWAIT(n) asm volatile("s_waitcnt vmcnt(" #n ")" ::: "memory")
#define SB() __builtin_amdgcn_sched_barrier(0)

__device__ __forceinline__ u16 f2bf(float f) {  // RNE
  union { float f; unsigned u; } v; v.f = f;
  unsigned r = v.u + 0x7fff + ((v.u >> 16) & 1);
  return (u16)(r >> 16);
}
__device__ __forceinline__ unsigned cvt2(float a, float b) {  // HW pack fp32x2->bf16x2
  __hip_bfloat162 v = __float22bfloat162_rn(make_float2(a, b));
  return *reinterpret_cast<unsigned*>(&v);
}
__device__ __forceinline__ short8 pack8(const float* __restrict__ p) {
  float4 a = *(const float4*)p, b = *(const float4*)(p + 4);
  union { unsigned u[4]; short8 s; } r;
  r.u[0] = cvt2(a.x, a.y); r.u[1] = cvt2(a.z, a.w);
  r.u[2] = cvt2(b.x, b.y); r.u[3] = cvt2(b.z, b.w);
  return r.s;
}
// async global->LDS, 16B per lane: LDS dest = uniform base + lane*16;
// global src = per-lane address. Explicit addrspace casts (addrspacecast).
__device__ __forceinline__ void gll16(const u16* g, u16* l) {
  __builtin_amdgcn_global_load_lds(
      (__attribute__((address_space(1))) void*)g,
      (__attribute__((address_space(3))) void*)l, 16, 0, 0);
}

// C/D map discovery (r10-verified contract); layout-map-free probes.
__device__ __forceinline__ void mfma_cdmap(int lane, int* rowm, int* colm) {
  const int c0 = lane & 15;
  union { u16 u[8]; short8 s; } a1, b1, a2, b2;
  const u16 one = f2bf(1.f), cid = f2bf((float)c0);
  #pragma unroll
  for (int j = 0; j < 8; ++j) { a1.u[j] = cid; b1.u[j] = one; a2.u[j] = one; b2.u[j] = cid; }
  floatx4 z = {0.f, 0.f, 0.f, 0.f};
  floatx4 dr = __builtin_amdgcn_mfma_f32_16x16x32_bf16(a1.s, b1.s, z, 0, 0, 0);
  floatx4 dc = __builtin_amdgcn_mfma_f32_16x16x32_bf16(a2.s, b2.s, z, 0, 0, 0);
  #pragma unroll
  for (int r = 0; r < 4; ++r) {
    rowm[r] = (int)(dr[r] * 0.03125f + 0.5f);
    colm[r] = (int)(dc[r] * 0.03125f + 0.5f);
  }
}

// ---------------------------------------------------------------------------
// k_ab: A (64 MB) -> Abits (2 MB bitmask)  [all 2048 blocks; coalesced]
//       + W -> Wf bf16 fragment pack       [blocks 0..15]   (R10-verified)
// ---------------------------------------------------------------------------
__global__ __launch_bounds__(256) void k_ab(const int* __restrict__ A,
                                            unsigned* __restrict__ Abits,
                                            const float* __restrict__ W,
                                            u16* __restrict__ Wf) {
  const int t = threadIdx.x;
  const int g = blockIdx.x * 256 + t;   // 524288 threads
  const int lane = t & 63;
  #pragma unroll
  for (int r = 0; r < 8; ++r) {
    const size_t gi = (size_t)r * 524288 + g;     // int4 index
    int4 v = *(const int4*)(A + gi * 4);
    unsigned nib = (v.x > 0 ? 1u : 0u) | (v.y > 0 ? 2u : 0u)
                 | (v.z > 0 ? 4u : 0u) | (v.w > 0 ? 8u : 0u);
    unsigned part = nib << ((lane & 7) * 4);
    part |= __shfl_xor(part, 1, 64);
    part |= __shfl_xor(part, 2, 64);
    part |= __shfl_xor(part, 4, 64);
    if ((lane & 7) == 0) Abits[gi >> 3] = part;
  }
  if (blockIdx.x < 16) {   // W pack
    const int col = g >> 4, kblock = g & 15;
    const int cg = col >> 6, nt = (col >> 4) & 3, c0 = col & 15;
    const float* src = W + (size_t)col * DIN + kblock * 32;
    u16* dst = Wf + ((size_t)(cg * 4 + nt) * 16 + kblock) * 512 + c0 * 8;
    #pragma unroll
    for (int q = 0; q < 4; ++q) {
      short8 v = pack8(src + q * 8);
      *(short8*)(dst + q * 128) = v;
    }
  }
}

// ---------------------------------------------------------------------------
// K1 (R12-verified decomposed form): grid 1024 = (tile, cg); 256 thr = 4 waves.
// ---------------------------------------------------------------------------
__global__ __launch_bounds__(256) void k1_wh(
    const float* __restrict__ h, const u16* __restrict__ Wf,
    const float* __restrict__ attn,
    u16* __restrict__ WhTf, float* __restrict__ s1g, float2* __restrict__ bdg)
{
  const int bid = blockIdx.x;           // 1024 blocks
  const int tile = bid >> 2, cg = bid & 3;
  const int i0 = tile * 16;
  const int t = threadIdx.x;            // 256 threads = 4 waves
  const int wv = t >> 6, lane = t & 63, q = lane >> 4, c0 = lane & 15;
  const int nt = wv;                    // wave owns cols [cg*64+nt*16, +16)
  int rowm[4], colm[4];
  mfma_cdmap(lane, rowm, colm);

  __shared__ u16  hT[16][DIN + 8];
  __shared__ float pS[16][HD + 4];      // 16 x 64 Wh stripe (head cg)

  #pragma unroll
  for (int rep = 0; rep < 4; ++rep) {   // stage h-tile coalesced (bf16)
    const int idx = rep * 256 + t;
    const int row = idx >> 6, c8 = (idx & 63) * 8;
    const float* hp = h + (size_t)(i0 + row) * DIN + c8;
    float4 a = *(const float4*)hp;
    float4 b = *(const float4*)(hp + 4);
    union { unsigned u[4]; int4 v; } pk;
    pk.u[0] = cvt2(a.x, a.y); pk.u[1] = cvt2(a.z, a.w);
    pk.u[2] = cvt2(b.x, b.y); pk.u[3] = cvt2(b.z, b.w);
    *(int4*)&hT[row][c8] = pk.v;
  }
  __syncthreads();

  floatx4 acc = {0.f, 0.f, 0.f, 0.f};
  #pragma unroll
  for (int ks = 0; ks < 16; ++ks) {     // full K=512, one nt per wave
    const int kb = ks * 32 + q * 8;
    short8 af = *(const short8*)&hT[c0][kb];
    short8 bf = *(const short8*)(Wf + ((size_t)(cg * 4 + nt) * 16 + ks) * 512 + lane * 8);
    acc = __builtin_amdgcn_mfma_f32_16x16x32_bf16(af, bf, acc, 0, 0, 0);
  }
  #pragma unroll
  for (int r = 0; r < 4; ++r)
    pS[rowm[r]][nt * 16 + colm[r]] = acc[r];
  __syncthreads();

  if (wv == 0) {   // s1/s2 for head cg
    const int r = lane & 15, qt = lane >> 4;
    float s1 = 0.f, s2 = 0.f;
    #pragma unroll
    for (int dd = 0; dd < 16; ++dd) {
      const int d = qt * 16 + dd;
      float v = pS[r][d];
      s1 += v * attn[cg * 128 + d];
      s2 += v * attn[cg * 128 + 64 + d];
    }
    s1 += __shfl_xor(s1, 16, 64); s1 += __shfl_xor(s1, 32, 64);
    s2 += __shfl_xor(s2, 16, 64); s2 += __shfl_xor(s2, 32, 64);
    if (lane < 16) {
      s1g[cg * L_ + i0 + r] = s1;
      bdg[cg * L_ + i0 + r] = make_float2(__expf(s2), __expf(0.2f * s2));
    }
  }
  if (wv == 1) {   // WhTf stripe store
    const int dl = t - 64;
    const int nt2 = dl >> 4, dc0 = dl & 15;
    const int jblock = i0 >> 5, qbase = (i0 & 31) >> 3;
    u16* base = WhTf + ((size_t)(cg * 4 + nt2) * JW + jblock) * 512 + dc0 * 8;
    #pragma unroll
    for (int jh = 0; jh < 2; ++jh) {
      const int i = jh * 8;
      union { unsigned u[4]; int4 v; } pk;
      pk.u[0] = cvt2(pS[i + 0][dl], pS[i + 1][dl]);
      pk.u[1] = cvt2(pS[i + 2][dl], pS[i + 3][dl]);
      pk.u[2] = cvt2(pS[i + 4][dl], pS[i + 5][dl]);
      pk.u[3] = cvt2(pS[i + 6][dl], pS[i + 7][dl]);
      *(int4*)(base + (qbase + jh) * 128) = pk.v;
    }
  }
}

// ---------------------------------------------------------------------------
// K2: masked softmax + PV + fused projection.  THIS ROUND:
//  W-fragment stream staged via async global_load_lds into PER-WAVE LDS
//  double-buffers (16 waves x 2 x 4 KB = 128 KB, dynamic LDS). The prefetch
//  cannot be sunk-to-use by the compiler (LDS-destined) - the structural fix
//  for the latency chain that defeated R2/R3/R5/R6 pipelining attempts.
//  Counted VMWAIT(4) drains exactly the 4 glls of the current buffer and
//  keeps the 4 newest VMEM ops (this kt's bd loads) in flight; per-iter VMEM
//  sequence is fixed (4 bd + 4 gll, #pragma unroll 1) so the count is exact.
//  No barriers inside the loop (buffers are wave-private); one post-loop
//  __syncthreads before the reduction arrays overlay the staging region.
// Dynamic LDS layout (139392 B):
//   [0      .. 131072)  stgW  [2][16 waves][4 nt][512 u16]
//   [131072 .. 139392)  AbitL [16][130] u32
//   phase-2 overlay into [0..44544): pA,pB,dden,rcpS,CnL
// ---------------------------------------------------------------------------
#define STG_U16_BUF   32768          // u16 per buffer (64 KB)
#define ABIT_OFF      131072
#define DYN_LDS_BYTES 139392

__global__ __launch_bounds__(1024) void k2_attn(
    const unsigned* __restrict__ Abits, const u16* __restrict__ WhTf,
    const float* __restrict__ s1g, const float2* __restrict__ bdg,
    const float* __restrict__ out_w, const float* __restrict__ out_b,
    float* __restrict__ out)
{
  extern __shared__ char dynLds[];
  u16* stgW = (u16*)dynLds;
  unsigned (*AbitL)[130] = (unsigned(*)[130])(dynLds + ABIT_OFF);

  const int i0 = blockIdx.x * 16;
  const int t = threadIdx.x;
  const int wv = t >> 6, lane = t & 63, q = lane >> 4, c0 = lane & 15;
  const int hd = wv & 3, jc = wv >> 2;

  {  // prologue: stage this block's 16 rows of the bitmask (8 KB, coalesced)
    const int row = t >> 6, l = t & 63;
    uint2 w2 = *(const uint2*)&Abits[(size_t)(i0 + row) * JW + l * 2];
    AbitL[row][l * 2] = w2.x;
    AbitL[row][l * 2 + 1] = w2.y;
  }
  int rowm[4], colm[4];
  mfma_cdmap(lane, rowm, colm);
  __syncthreads();

  const float s1v = s1g[hd * L_ + i0 + c0];
  const float av = __expf(s1v);          // exp(s1)
  const float cv = __expf(0.2f * s1v);   // exp(0.2*s1)
  const float th = __expf(-s1v);         // b >= th  <=>  s1+s2 >= 0
  const float2* bdh = bdg + (size_t)hd * L_ + jc * 1024;
  const u16* Wc = WhTf + (size_t)(hd * 4) * JW * 512 + (size_t)(jc * 32) * 512 + lane * 8;

  u16* stg0 = stgW + (size_t)wv * 2048;                 // buf0, my wave
  u16* stg1 = stgW + STG_U16_BUF + (size_t)wv * 2048;   // buf1, my wave

  floatx4 acc[4] = {};
  float dpart = 0.f;
  union PF { unsigned u[4]; short8 s; };

  // prime buf0 with kt=0 (4 x 1KB async copies)
  #pragma unroll
  for (int nt = 0; nt < 4; ++nt)
    gll16(Wc + (size_t)nt * JW * 512, stg0 + nt * 512);

  #pragma unroll 1
  for (int kt = 0; kt < 32; ++kt) {
    u16* cur = (kt & 1) ? stg1 : stg0;
    u16* nxt = (kt & 1) ? stg0 : stg1;
    // bd loads for this kt (newest 4 VMEM ops -> kept by VMWAIT(4))
    const float2* p = bdh + kt * 32 + q * 8;
    float4 v0 = *(const float4*)p;
    float4 v1 = *(const float4*)(p + 2);
    float4 v2 = *(const float4*)(p + 4);
    float4 v3 = *(const float4*)(p + 6);
    // drain everything except the 4 bd loads (i.e. the glls for `cur`)
    VMWAIT(4); SB();
    short8 w0 = *(const short8*)(cur + 0 * 512 + lane * 8);
    short8 w1 = *(const short8*)(cur + 1 * 512 + lane * 8);
    short8 w2 = *(const short8*)(cur + 2 * 512 + lane * 8);
    short8 w3 = *(const short8*)(cur + 3 * 512 + lane * 8);
    if (kt < 31) {   // async prefetch kt+1 into the other buffer
      const u16* src = Wc + (size_t)(kt + 1) * 512;
      #pragma unroll
      for (int nt = 0; nt < 4; ++nt)
        gll16(src + (size_t)nt * JW * 512, nxt + nt * 512);
    }
    SB();
    const unsigned mb = (AbitL[c0][jc * 32 + kt] >> (q * 8)) & 0xffu;
    float e0 = (v0.x >= th) ? (av * v0.x) : (cv * v0.y);
    float e1 = (v0.z >= th) ? (av * v0.z) : (cv * v0.w);
    float e2 = (v1.x >= th) ? (av * v1.x) : (cv * v1.y);
    float e3 = (v1.z >= th) ? (av * v1.z) : (cv * v1.w);
    float e4 = (v2.x >= th) ? (av * v2.x) : (cv * v2.y);
    float e5 = (v2.z >= th) ? (av * v2.z) : (cv * v2.w);
    float e6 = (v3.x >= th) ? (av * v3.x) : (cv * v3.y);
    float e7 = (v3.z >= th) ? (av * v3.z) : (cv * v3.w);
    e0 = (mb & 1u)   ? e0 : 0.f;
    e1 = (mb & 2u)   ? e1 : 0.f;
    e2 = (mb & 4u)   ? e2 : 0.f;
    e3 = (mb & 8u)   ? e3 : 0.f;
    e4 = (mb & 16u)  ? e4 : 0.f;
    e5 = (mb & 32u)  ? e5 : 0.f;
    e6 = (mb & 64u)  ? e6 : 0.f;
    e7 = (mb & 128u) ? e7 : 0.f;
    dpart += ((e0 + e1) + (e2 + e3)) + ((e4 + e5) + (e6 + e7));
    PF pf;
    pf.u[0] = cvt2(e0, e1); pf.u[1] = cvt2(e2, e3);
    pf.u[2] = cvt2(e4, e5); pf.u[3] = cvt2(e6, e7);
    acc[0] = __builtin_amdgcn_mfma_f32_16x16x32_bf16(pf.s, w0, acc[0], 0, 0, 0);
    acc[1] = __builtin_amdgcn_mfma_f32_16x16x32_bf16(pf.s, w1, acc[1], 0, 0, 0);
    acc[2] = __builtin_amdgcn_mfma_f32_16x16x32_bf16(pf.s, w2, acc[2], 0, 0, 0);
    acc[3] = __builtin_amdgcn_mfma_f32_16x16x32_bf16(pf.s, w3, acc[3], 0, 0, 0);
  }

  // partial denom of row c0 over this j-chunk (registers only)
  dpart += __shfl_xor(dpart, 16, 64);
  dpart += __shfl_xor(dpart, 32, 64);

  __syncthreads();   // all waves done reading stg -> safe to overlay

  // phase-2 overlay pointers (alias the staging region)
  float (*pA)[16][HD + 4]  = (float(*)[16][HD + 4])(dynLds);
  float (*pB)[16][HD + 4]  = (float(*)[16][HD + 4])(dynLds + 17408);
  float (*dden)[4][16]     = (float(*)[4][16])(dynLds + 34816);
  float (*rcpS)[16]        = (float(*)[16])(dynLds + 35840);
  u16  (*CnL)[DOUT + 8]    = (u16(*)[DOUT + 8])(dynLds + 36096);

  if (lane < 16) dden[hd][jc][lane] = dpart;

  auto writeT = [&](float (*P)[HD + 4]) {
    #pragma unroll
    for (int nt = 0; nt < 4; ++nt)
      #pragma unroll
      for (int r = 0; r < 4; ++r)
        P[rowm[r]][nt * 16 + colm[r]] = acc[nt][r];
  };
  auto addB2A = [&]() {
    const int h2 = t >> 8, rem = t & 255, row = rem >> 4, d4 = (rem & 15) * 4;
    float4* a = (float4*)&pA[h2][row][d4];
    float4 bv = *(float4*)&pB[h2][row][d4];
    float4 av2 = *a;
    av2.x += bv.x; av2.y += bv.y; av2.z += bv.z; av2.w += bv.w;
    *a = av2;
  };

  if (jc == 0) writeT(pA[hd]);
  if (jc == 1) writeT(pB[hd]);
  __syncthreads();
  if (t < 64) {
    const int hh = t >> 4, r = t & 15;
    float den = dden[hh][0][r] + dden[hh][1][r] + dden[hh][2][r] + dden[hh][3][r];
    rcpS[hh][r] = (den > 0.f) ? (1.f / den) : 0.f;  // empty row -> out = bias
  }
  addB2A();
  __syncthreads();
  if (jc == 2) writeT(pB[hd]);
  __syncthreads();
  addB2A();
  __syncthreads();
  if (jc == 3) writeT(pB[hd]);
  __syncthreads();
  addB2A();
  __syncthreads();

  {  // Cn (bf16)
    const int row = t >> 6, c4 = (t & 63) * 4;
    #pragma unroll
    for (int x = 0; x < 4; ++x) {
      const int col = c4 + x;
      const int hh = col >> 6, d = col & 63;
      CnL[row][col] = f2bf(pA[hh][row][d] * rcpS[hh][row]);
    }
  }
  __syncthreads();

  if (wv < 4) {  // projection: Out2(16x256) = Cn @ out_w.T
    const int cg = wv;
    floatx4 o[4] = {};
    #pragma unroll
    for (int kt = 0; kt < DOUT / 32; ++kt) {
      const int kb2 = kt * 32 + q * 8;
      short8 afr = *(const short8*)(&CnL[c0][kb2]);
      #pragma unroll
      for (int nt = 0; nt < 4; ++nt) {
        const int col = cg * 64 + nt * 16 + c0;
        short8 bfo = pack8(out_w + (size_t)col * DOUT + kb2);
        o[nt] = __builtin_amdgcn_mfma_f32_16x16x32_bf16(afr, bfo, o[nt], 0, 0, 0);
      }
    }
    #pragma unroll
    for (int nt = 0; nt < 4; ++nt)
      #pragma unroll
      for (int r = 0; r < 4; ++r) {
        const int col = cg * 64 + nt * 16 + colm[r];
        out[(size_t)(i0 + rowm[r]) * DOUT + col] = o[nt][r] + out_b[col];
      }
  }
}

// ---------------------------------------------------------------------------
extern "C" void kernel_launch(void* const* d_in, const int* in_sizes, int n_in,
                              void* d_out, int out_size, void* d_ws, size_t ws_size,
                              hipStream_t stream) {
  const float* h     = (const float*)d_in[0];   // (4096, 512) fp32
  const int*   A     = (const int*)d_in[1];     // (4096, 4096) int32
  const float* W     = (const float*)d_in[2];   // (256, 512) fp32
  const float* attn  = (const float*)d_in[3];   // (4, 128) fp32
  const float* out_w = (const float*)d_in[4];   // (256, 256) fp32
  const float* out_b = (const float*)d_in[5];   // (256,) fp32
  float* outp = (float*)d_out;                  // (4096, 256) fp32

  // ws: WhTf bf16 (2 MB) | s1 f32 (64 KB) | bd float2 (128 KB) | Abits (2 MB)
  const size_t WHTF_B  = (size_t)DOUT * L_ * 2;          // 2097152
  const size_t S1_B    = (size_t)NH * L_ * 4;            // 65536
  const size_t BD_B    = (size_t)NH * L_ * 8;            // 131072
  const size_t ABITS_B = (size_t)L_ * JW * 4;            // 2097152
  const size_t AB_OFF  = WHTF_B + S1_B + BD_B;

  u16*    WhTf = (u16*)d_ws;
  float*  s1g  = (float*)((char*)d_ws + WHTF_B);
  float2* bdg  = (float2*)((char*)d_ws + WHTF_B + S1_B);
  unsigned* Abits = (ws_size >= AB_OFF + ABITS_B)
                  ? (unsigned*)((char*)d_ws + AB_OFF)
                  : (unsigned*)((char*)d_out + 2097152);
  u16* Wf = (u16*)d_out;   // k_ab -> k1 -> k2 serialize; k2 overwrites d_out last

  // allow >64 KB dynamic LDS for k2 (idempotent; not a stream op, graph-safe)
  static bool attr_set = false;
  if (!attr_set) {
    hipFuncSetAttribute(reinterpret_cast<const void*>(k2_attn),
                        hipFuncAttributeMaxDynamicSharedMemorySize,
                        DYN_LDS_BYTES);
    attr_set = true;
  }

  hipLaunchKernelGGL(k_ab, dim3(2048), dim3(256), 0, stream, A, Abits, W, Wf);
  hipLaunchKernelGGL(k1_wh, dim3(L_ / 16 * 4), dim3(256), 0, stream,
                     h, Wf, attn, WhTf, s1g, bdg);
  hipLaunchKernelGGL(k2_attn, dim3(L_ / 16), dim3(1024), DYN_LDS_BYTES, stream,
                     Abits, WhTf, s1g, bdg, out_w, out_b, outp);
}

// Round 14
// 153.648 us; speedup vs baseline: 1.0285x; 1.0285x over previous
//
#include <hip/hip_runtime.h>
#include <hip/hip_bf16.h>

#define L_    4096
#define DIN   512
#define DOUT  256
#define NH    4
#define HD    64
#define JW    128                      // L_/32 j-words per row

typedef unsigned short u16;
typedef __attribute__((ext_vector_type(8))) short short8;   // 8 x bf16
typedef __attribute__((ext_vector_type(4))) float floatx4;  // MFMA C/D frag

#define VMWAIT(n) asm volatile("s_waitcnt vmcnt(" #n ")" ::: "memory")
#define SB() __builtin_amdgcn_sched_barrier(0)

__device__ __forceinline__ u16 f2bf(float f) {  // RNE
  union { float f; unsigned u; } v; v.f = f;
  unsigned r = v.u + 0x7fff + ((v.u >> 16) & 1);
  return (u16)(r >> 16);
}
__device__ __forceinline__ unsigned cvt2(float a, float b) {  // HW pack fp32x2->bf16x2
  __hip_bfloat162 v = __float22bfloat162_rn(make_float2(a, b));
  return *reinterpret_cast<unsigned*>(&v);
}
__device__ __forceinline__ short8 pack8(const float* __restrict__ p) {
  float4 a = *(const float4*)p, b = *(const float4*)(p + 4);
  union { unsigned u[4]; short8 s; } r;
  r.u[0] = cvt2(a.x, a.y); r.u[1] = cvt2(a.z, a.w);
  r.u[2] = cvt2(b.x, b.y); r.u[3] = cvt2(b.z, b.w);
  return r.s;
}
// async global->LDS. 16B/lane and 4B/lane variants; LDS dest wave-uniform,
// global src per-lane (guide-verified semantics, R13-verified in this kernel).
__device__ __forceinline__ void gll16(const u16* g, u16* l) {
  __builtin_amdgcn_global_load_lds(
      (__attribute__((address_space(1))) void*)g,
      (__attribute__((address_space(3))) void*)l, 16, 0, 0);
}
__device__ __forceinline__ void gll4(const void* g, void* l) {
  __builtin_amdgcn_global_load_lds(
      (__attribute__((address_space(1))) void*)g,
      (__attribute__((address_space(3))) void*)l, 4, 0, 0);
}

// C/D map discovery (r10-verified contract); layout-map-free probes.
__device__ __forceinline__ void mfma_cdmap(int lane, int* rowm, int* colm) {
  const int c0 = lane & 15;
  union { u16 u[8]; short8 s; } a1, b1, a2, b2;
  const u16 one = f2bf(1.f), cid = f2bf((float)c0);
  #pragma unroll
  for (int j = 0; j < 8; ++j) { a1.u[j] = cid; b1.u[j] = one; a2.u[j] = one; b2.u[j] = cid; }
  floatx4 z = {0.f, 0.f, 0.f, 0.f};
  floatx4 dr = __builtin_amdgcn_mfma_f32_16x16x32_bf16(a1.s, b1.s, z, 0, 0, 0);
  floatx4 dc = __builtin_amdgcn_mfma_f32_16x16x32_bf16(a2.s, b2.s, z, 0, 0, 0);
  #pragma unroll
  for (int r = 0; r < 4; ++r) {
    rowm[r] = (int)(dr[r] * 0.03125f + 0.5f);
    colm[r] = (int)(dc[r] * 0.03125f + 0.5f);
  }
}

// ---------------------------------------------------------------------------
// k_ab: A (64 MB) -> Abits (2 MB bitmask)  [all 2048 blocks; coalesced]
//       + W -> Wf bf16 fragment pack       [blocks 0..15]   (R10-verified)
// ---------------------------------------------------------------------------
__global__ __launch_bounds__(256) void k_ab(const int* __restrict__ A,
                                            unsigned* __restrict__ Abits,
                                            const float* __restrict__ W,
                                            u16* __restrict__ Wf) {
  const int t = threadIdx.x;
  const int g = blockIdx.x * 256 + t;   // 524288 threads
  const int lane = t & 63;
  #pragma unroll
  for (int r = 0; r < 8; ++r) {
    const size_t gi = (size_t)r * 524288 + g;     // int4 index
    int4 v = *(const int4*)(A + gi * 4);
    unsigned nib = (v.x > 0 ? 1u : 0u) | (v.y > 0 ? 2u : 0u)
                 | (v.z > 0 ? 4u : 0u) | (v.w > 0 ? 8u : 0u);
    unsigned part = nib << ((lane & 7) * 4);
    part |= __shfl_xor(part, 1, 64);
    part |= __shfl_xor(part, 2, 64);
    part |= __shfl_xor(part, 4, 64);
    if ((lane & 7) == 0) Abits[gi >> 3] = part;
  }
  if (blockIdx.x < 16) {   // W pack
    const int col = g >> 4, kblock = g & 15;
    const int cg = col >> 6, nt = (col >> 4) & 3, c0 = col & 15;
    const float* src = W + (size_t)col * DIN + kblock * 32;
    u16* dst = Wf + ((size_t)(cg * 4 + nt) * 16 + kblock) * 512 + c0 * 8;
    #pragma unroll
    for (int q = 0; q < 4; ++q) {
      short8 v = pack8(src + q * 8);
      *(short8*)(dst + q * 128) = v;
    }
  }
}

// ---------------------------------------------------------------------------
// K1 (R12-verified decomposed form): grid 1024 = (tile, cg); 256 thr = 4 waves.
// ---------------------------------------------------------------------------
__global__ __launch_bounds__(256) void k1_wh(
    const float* __restrict__ h, const u16* __restrict__ Wf,
    const float* __restrict__ attn,
    u16* __restrict__ WhTf, float* __restrict__ s1g, float2* __restrict__ bdg)
{
  const int bid = blockIdx.x;           // 1024 blocks
  const int tile = bid >> 2, cg = bid & 3;
  const int i0 = tile * 16;
  const int t = threadIdx.x;            // 256 threads = 4 waves
  const int wv = t >> 6, lane = t & 63, q = lane >> 4, c0 = lane & 15;
  const int nt = wv;                    // wave owns cols [cg*64+nt*16, +16)
  int rowm[4], colm[4];
  mfma_cdmap(lane, rowm, colm);

  __shared__ u16  hT[16][DIN + 8];
  __shared__ float pS[16][HD + 4];      // 16 x 64 Wh stripe (head cg)

  #pragma unroll
  for (int rep = 0; rep < 4; ++rep) {   // stage h-tile coalesced (bf16)
    const int idx = rep * 256 + t;
    const int row = idx >> 6, c8 = (idx & 63) * 8;
    const float* hp = h + (size_t)(i0 + row) * DIN + c8;
    float4 a = *(const float4*)hp;
    float4 b = *(const float4*)(hp + 4);
    union { unsigned u[4]; int4 v; } pk;
    pk.u[0] = cvt2(a.x, a.y); pk.u[1] = cvt2(a.z, a.w);
    pk.u[2] = cvt2(b.x, b.y); pk.u[3] = cvt2(b.z, b.w);
    *(int4*)&hT[row][c8] = pk.v;
  }
  __syncthreads();

  floatx4 acc = {0.f, 0.f, 0.f, 0.f};
  #pragma unroll
  for (int ks = 0; ks < 16; ++ks) {     // full K=512, one nt per wave
    const int kb = ks * 32 + q * 8;
    short8 af = *(const short8*)&hT[c0][kb];
    short8 bf = *(const short8*)(Wf + ((size_t)(cg * 4 + nt) * 16 + ks) * 512 + lane * 8);
    acc = __builtin_amdgcn_mfma_f32_16x16x32_bf16(af, bf, acc, 0, 0, 0);
  }
  #pragma unroll
  for (int r = 0; r < 4; ++r)
    pS[rowm[r]][nt * 16 + colm[r]] = acc[r];
  __syncthreads();

  if (wv == 0) {   // s1/s2 for head cg
    const int r = lane & 15, qt = lane >> 4;
    float s1 = 0.f, s2 = 0.f;
    #pragma unroll
    for (int dd = 0; dd < 16; ++dd) {
      const int d = qt * 16 + dd;
      float v = pS[r][d];
      s1 += v * attn[cg * 128 + d];
      s2 += v * attn[cg * 128 + 64 + d];
    }
    s1 += __shfl_xor(s1, 16, 64); s1 += __shfl_xor(s1, 32, 64);
    s2 += __shfl_xor(s2, 16, 64); s2 += __shfl_xor(s2, 32, 64);
    if (lane < 16) {
      s1g[cg * L_ + i0 + r] = s1;
      bdg[cg * L_ + i0 + r] = make_float2(__expf(s2), __expf(0.2f * s2));
    }
  }
  if (wv == 1) {   // WhTf stripe store
    const int dl = t - 64;
    const int nt2 = dl >> 4, dc0 = dl & 15;
    const int jblock = i0 >> 5, qbase = (i0 & 31) >> 3;
    u16* base = WhTf + ((size_t)(cg * 4 + nt2) * JW + jblock) * 512 + dc0 * 8;
    #pragma unroll
    for (int jh = 0; jh < 2; ++jh) {
      const int i = jh * 8;
      union { unsigned u[4]; int4 v; } pk;
      pk.u[0] = cvt2(pS[i + 0][dl], pS[i + 1][dl]);
      pk.u[1] = cvt2(pS[i + 2][dl], pS[i + 3][dl]);
      pk.u[2] = cvt2(pS[i + 4][dl], pS[i + 5][dl]);
      pk.u[3] = cvt2(pS[i + 6][dl], pS[i + 7][dl]);
      *(int4*)(base + (qbase + jh) * 128) = pk.v;
    }
  }
}

// ---------------------------------------------------------------------------
// K2: masked softmax + PV + fused projection.  THIS ROUND:
//  BOTH hot-loop streams go through global_load_lds: per wave per kt,
//  4x gll16 for the W fragments (4 KB) + 1x gll4 for the 256 B bd chunk.
//  -> the loop contains EXACTLY 5 VMEM ops per iteration and zero plain
//  global loads, so the counted VMWAIT(5) is bulletproof (builtins with LDS
//  side effects can't be sunk/reordered - the R2/R3/R6 failure mode, and
//  R13's zero-cover bd loads, are both eliminated).
//  Distance-1 double-buffer: iter kt issues gll5(kt+1) into the OTHER
//  buffer (no read/write race), VMWAIT(5) drains exactly gll5(kt).
//  Last iteration peeled with VMWAIT(0).
// Dynamic LDS layout (147584 B, 1 block/CU):
//   [0      .. 131072)  stgW  [2][16 waves][4 nt][512 u16]
//   [131072 .. 139264)  stgB  [2][16 waves][64 float]
//   [139264 .. 147584)  AbitL [16][130] u32
//   phase-2 overlay into [0..44544): pA,pB,dden,rcpS,CnL
// ---------------------------------------------------------------------------
#define STGB_OFF      131072
#define ABIT_OFF2     139264
#define DYN_LDS_BYTES 147584

__global__ __launch_bounds__(1024) void k2_attn(
    const unsigned* __restrict__ Abits, const u16* __restrict__ WhTf,
    const float* __restrict__ s1g, const float2* __restrict__ bdg,
    const float* __restrict__ out_w, const float* __restrict__ out_b,
    float* __restrict__ out)
{
  extern __shared__ char dynLds[];
  unsigned (*AbitL)[130] = (unsigned(*)[130])(dynLds + ABIT_OFF2);

  const int i0 = blockIdx.x * 16;
  const int t = threadIdx.x;
  const int wv = t >> 6, lane = t & 63, q = lane >> 4, c0 = lane & 15;
  const int hd = wv & 3, jc = wv >> 2;

  {  // prologue: stage this block's 16 rows of the bitmask (8 KB, coalesced)
    const int row = t >> 6, l = t & 63;
    uint2 w2 = *(const uint2*)&Abits[(size_t)(i0 + row) * JW + l * 2];
    AbitL[row][l * 2] = w2.x;
    AbitL[row][l * 2 + 1] = w2.y;
  }
  int rowm[4], colm[4];
  mfma_cdmap(lane, rowm, colm);
  __syncthreads();

  const float s1v = s1g[hd * L_ + i0 + c0];
  const float av = __expf(s1v);          // exp(s1)
  const float cv = __expf(0.2f * s1v);   // exp(0.2*s1)
  const float th = __expf(-s1v);         // b >= th  <=>  s1+s2 >= 0
  const float2* bdh = bdg + (size_t)hd * L_ + jc * 1024;
  const u16* Wc = WhTf + (size_t)(hd * 4) * JW * 512 + (size_t)(jc * 32) * 512 + lane * 8;

  u16* stgW0 = (u16*)dynLds + (size_t)wv * 2048;           // buf0 W (4 KB/wave)
  u16* stgW1 = (u16*)dynLds + 32768 + (size_t)wv * 2048;   // buf1 W
  float* stgB0 = (float*)(dynLds + STGB_OFF) + wv * 64;    // buf0 bd (256 B/wave)
  float* stgB1 = (float*)(dynLds + STGB_OFF + 4096) + wv * 64;

  auto gllW = [&](int kt, u16* dst) {    // 4 x 1KB async
    const u16* src = Wc + (size_t)kt * 512;
    #pragma unroll
    for (int nt = 0; nt < 4; ++nt)
      gll16(src + (size_t)nt * JW * 512, dst + nt * 512);
  };
  auto gllB = [&](int kt, float* dst) {  // 256 B async (64 lanes x 4B)
    const char* src = (const char*)(bdh + kt * 32) + lane * 4;
    gll4(src, dst);
  };

  floatx4 acc[4] = {};
  float dpart = 0.f;
  union PF { unsigned u[4]; short8 s; };

  auto phase = [&](const u16* wbuf, const float* bbuf, int kt) {
    short8 w0 = *(const short8*)(wbuf + 0 * 512 + lane * 8);
    short8 w1 = *(const short8*)(wbuf + 1 * 512 + lane * 8);
    short8 w2 = *(const short8*)(wbuf + 2 * 512 + lane * 8);
    short8 w3 = *(const short8*)(wbuf + 3 * 512 + lane * 8);
    const float* bl = bbuf + q * 16;     // this q-group's 8 j's (broadcast)
    float4 v0 = *(const float4*)(bl + 0);
    float4 v1 = *(const float4*)(bl + 4);
    float4 v2 = *(const float4*)(bl + 8);
    float4 v3 = *(const float4*)(bl + 12);
    const unsigned mb = (AbitL[c0][jc * 32 + kt] >> (q * 8)) & 0xffu;
    float e0 = (v0.x >= th) ? (av * v0.x) : (cv * v0.y);
    float e1 = (v0.z >= th) ? (av * v0.z) : (cv * v0.w);
    float e2 = (v1.x >= th) ? (av * v1.x) : (cv * v1.y);
    float e3 = (v1.z >= th) ? (av * v1.z) : (cv * v1.w);
    float e4 = (v2.x >= th) ? (av * v2.x) : (cv * v2.y);
    float e5 = (v2.z >= th) ? (av * v2.z) : (cv * v2.w);
    float e6 = (v3.x >= th) ? (av * v3.x) : (cv * v3.y);
    float e7 = (v3.z >= th) ? (av * v3.z) : (cv * v3.w);
    e0 = (mb & 1u)   ? e0 : 0.f;
    e1 = (mb & 2u)   ? e1 : 0.f;
    e2 = (mb & 4u)   ? e2 : 0.f;
    e3 = (mb & 8u)   ? e3 : 0.f;
    e4 = (mb & 16u)  ? e4 : 0.f;
    e5 = (mb & 32u)  ? e5 : 0.f;
    e6 = (mb & 64u)  ? e6 : 0.f;
    e7 = (mb & 128u) ? e7 : 0.f;
    dpart += ((e0 + e1) + (e2 + e3)) + ((e4 + e5) + (e6 + e7));
    PF pf;
    pf.u[0] = cvt2(e0, e1); pf.u[1] = cvt2(e2, e3);
    pf.u[2] = cvt2(e4, e5); pf.u[3] = cvt2(e6, e7);
    acc[0] = __builtin_amdgcn_mfma_f32_16x16x32_bf16(pf.s, w0, acc[0], 0, 0, 0);
    acc[1] = __builtin_amdgcn_mfma_f32_16x16x32_bf16(pf.s, w1, acc[1], 0, 0, 0);
    acc[2] = __builtin_amdgcn_mfma_f32_16x16x32_bf16(pf.s, w2, acc[2], 0, 0, 0);
    acc[3] = __builtin_amdgcn_mfma_f32_16x16x32_bf16(pf.s, w3, acc[3], 0, 0, 0);
  };

  // prime buf0 with kt=0 (5 VMEM)
  gllW(0, stgW0); gllB(0, stgB0);

  #pragma unroll 1
  for (int kt = 0; kt < 31; ++kt) {
    // prefetch kt+1 into the OTHER buffer (no race with this kt's reads)
    u16*   wn = (kt & 1) ? stgW0 : stgW1;
    float* bn = (kt & 1) ? stgB0 : stgB1;
    gllW(kt + 1, wn); gllB(kt + 1, bn);
    VMWAIT(5); SB();                    // drain gll5(kt); leave gll5(kt+1)
    const u16*   wc = (kt & 1) ? stgW1 : stgW0;
    const float* bc = (kt & 1) ? stgB1 : stgB0;
    phase(wc, bc, kt);
  }
  VMWAIT(0); SB();                      // drain gll5(31)
  phase(stgW1, stgB1, 31);              // kt=31 is odd -> buf1

  // partial denom of row c0 over this j-chunk (registers only)
  dpart += __shfl_xor(dpart, 16, 64);
  dpart += __shfl_xor(dpart, 32, 64);

  __syncthreads();   // all waves done reading stg -> safe to overlay

  // phase-2 overlay pointers (alias the staging region)
  float (*pA)[16][HD + 4]  = (float(*)[16][HD + 4])(dynLds);
  float (*pB)[16][HD + 4]  = (float(*)[16][HD + 4])(dynLds + 17408);
  float (*dden)[4][16]     = (float(*)[4][16])(dynLds + 34816);
  float (*rcpS)[16]        = (float(*)[16])(dynLds + 35840);
  u16  (*CnL)[DOUT + 8]    = (u16(*)[DOUT + 8])(dynLds + 36096);

  if (lane < 16) dden[hd][jc][lane] = dpart;

  auto writeT = [&](float (*P)[HD + 4]) {
    #pragma unroll
    for (int nt = 0; nt < 4; ++nt)
      #pragma unroll
      for (int r = 0; r < 4; ++r)
        P[rowm[r]][nt * 16 + colm[r]] = acc[nt][r];
  };
  auto addB2A = [&]() {
    const int h2 = t >> 8, rem = t & 255, row = rem >> 4, d4 = (rem & 15) * 4;
    float4* a = (float4*)&pA[h2][row][d4];
    float4 bv = *(float4*)&pB[h2][row][d4];
    float4 av2 = *a;
    av2.x += bv.x; av2.y += bv.y; av2.z += bv.z; av2.w += bv.w;
    *a = av2;
  };

  if (jc == 0) writeT(pA[hd]);
  if (jc == 1) writeT(pB[hd]);
  __syncthreads();
  if (t < 64) {
    const int hh = t >> 4, r = t & 15;
    float den = dden[hh][0][r] + dden[hh][1][r] + dden[hh][2][r] + dden[hh][3][r];
    rcpS[hh][r] = (den > 0.f) ? (1.f / den) : 0.f;  // empty row -> out = bias
  }
  addB2A();
  __syncthreads();
  if (jc == 2) writeT(pB[hd]);
  __syncthreads();
  addB2A();
  __syncthreads();
  if (jc == 3) writeT(pB[hd]);
  __syncthreads();
  addB2A();
  __syncthreads();

  {  // Cn (bf16)
    const int row = t >> 6, c4 = (t & 63) * 4;
    #pragma unroll
    for (int x = 0; x < 4; ++x) {
      const int col = c4 + x;
      const int hh = col >> 6, d = col & 63;
      CnL[row][col] = f2bf(pA[hh][row][d] * rcpS[hh][row]);
    }
  }
  __syncthreads();

  if (wv < 4) {  // projection: Out2(16x256) = Cn @ out_w.T
    const int cg = wv;
    floatx4 o[4] = {};
    #pragma unroll
    for (int kt = 0; kt < DOUT / 32; ++kt) {
      const int kb2 = kt * 32 + q * 8;
      short8 afr = *(const short8*)(&CnL[c0][kb2]);
      #pragma unroll
      for (int nt = 0; nt < 4; ++nt) {
        const int col = cg * 64 + nt * 16 + c0;
        short8 bfo = pack8(out_w + (size_t)col * DOUT + kb2);
        o[nt] = __builtin_amdgcn_mfma_f32_16x16x32_bf16(afr, bfo, o[nt], 0, 0, 0);
      }
    }
    #pragma unroll
    for (int nt = 0; nt < 4; ++nt)
      #pragma unroll
      for (int r = 0; r < 4; ++r) {
        const int col = cg * 64 + nt * 16 + colm[r];
        out[(size_t)(i0 + rowm[r]) * DOUT + col] = o[nt][r] + out_b[col];
      }
  }
}

// ---------------------------------------------------------------------------
extern "C" void kernel_launch(void* const* d_in, const int* in_sizes, int n_in,
                              void* d_out, int out_size, void* d_ws, size_t ws_size,
                              hipStream_t stream) {
  const float* h     = (const float*)d_in[0];   // (4096, 512) fp32
  const int*   A     = (const int*)d_in[1];     // (4096, 4096) int32
  const float* W     = (const float*)d_in[2];   // (256, 512) fp32
  const float* attn  = (const float*)d_in[3];   // (4, 128) fp32
  const float* out_w = (const float*)d_in[4];   // (256, 256) fp32
  const float* out_b = (const float*)d_in[5];   // (256,) fp32
  float* outp = (float*)d_out;                  // (4096, 256) fp32

  // ws: WhTf bf16 (2 MB) | s1 f32 (64 KB) | bd float2 (128 KB) | Abits (2 MB)
  const size_t WHTF_B  = (size_t)DOUT * L_ * 2;          // 2097152
  const size_t S1_B    = (size_t)NH * L_ * 4;            // 65536
  const size_t BD_B    = (size_t)NH * L_ * 8;            // 131072
  const size_t ABITS_B = (size_t)L_ * JW * 4;            // 2097152
  const size_t AB_OFF  = WHTF_B + S1_B + BD_B;

  u16*    WhTf = (u16*)d_ws;
  float*  s1g  = (float*)((char*)d_ws + WHTF_B);
  float2* bdg  = (float2*)((char*)d_ws + WHTF_B + S1_B);
  unsigned* Abits = (ws_size >= AB_OFF + ABITS_B)
                  ? (unsigned*)((char*)d_ws + AB_OFF)
                  : (unsigned*)((char*)d_out + 2097152);
  u16* Wf = (u16*)d_out;   // k_ab -> k1 -> k2 serialize; k2 overwrites d_out last

  // allow >64 KB dynamic LDS for k2 (idempotent; not a stream op, graph-safe)
  static bool attr_set = false;
  if (!attr_set) {
    hipFuncSetAttribute(reinterpret_cast<const void*>(k2_attn),
                        hipFuncAttributeMaxDynamicSharedMemorySize,
                        DYN_LDS_BYTES);
    attr_set = true;
  }

  hipLaunchKernelGGL(k_ab, dim3(2048), dim3(256), 0, stream, A, Abits, W, Wf);
  hipLaunchKernelGGL(k1_wh, dim3(L_ / 16 * 4), dim3(256), 0, stream,
                     h, Wf, attn, WhTf, s1g, bdg);
  hipLaunchKernelGGL(k2_attn, dim3(L_ / 16), dim3(1024), DYN_LDS_BYTES, stream,
                     Abits, WhTf, s1g, bdg, out_w, out_b, outp);
}